// Round 5
// baseline (1100.125 us; speedup 1.0000x reference)
//
#include <hip/hip_runtime.h>
#include <hip/hip_bf16.h>
#include <cstdint>
#include <cmath>

// ---------------------------------------------------------------------------
// TransLayer block: fused QKV proj -> exp(QK^T/sqrt(D)) -> PV/rowsum -> GELU FFN.
// B=8, N=2048, D=1028 (K-pad 1088, N-pad 1152), H=4112 (pad 4224).
// GEMMs: C = A @ B^T, K-contiguous bf16, fp32 acc, 128x128 tiles, BK=64,
// MFMA 16x16x32, XOR-swizzled LDS (0 bank conflicts, verified R3/R4).
// XCD-contiguous tile remap: b -> xcd=b&7 owns a contiguous logical range
// (x fastest) so each XCD's L2 keeps its A row-block resident.
// Softmax fused: score epilogue writes exp(s) + atomic row sums; PV epilogue
// scales by 1/l[row] (no max-subtraction needed: |logits| <~ 3).
// ---------------------------------------------------------------------------

typedef __bf16 bf16;
typedef __bf16 bf16x8 __attribute__((ext_vector_type(8)));
typedef float  f32x4  __attribute__((ext_vector_type(4)));

#define D_REAL   1028
#define D_PADK   1088   // K-dim pad (mult of 64)
#define D_PADN   1152
#define H_REAL   4112
#define H_PAD    4224
#define NTOK     2048
#define NB       8
#define MTOT     (NB*NTOK)               // 16384
#define SLAB_X   ((size_t)NTOK*D_PADK)
#define SLAB_S   ((size_t)NTOK*NTOK)
#define WSLAB    ((size_t)D_PADN*D_PADK)
#define VSLAB    ((size_t)D_PADN*NTOK)

__device__ __forceinline__ void async16(const void* g, void* l) {
    __builtin_amdgcn_global_load_lds(
        (__attribute__((address_space(1))) void*)(uintptr_t)g,
        (__attribute__((address_space(3))) void*)(uint32_t)(uintptr_t)l,
        16, 0, 0);
}

// EPI: 2 = exp(acc*scale)->bf16 + atomic row sums into lsum
//      3 = gelu(acc+bias)->bf16
//      4 = fp32 acc+bias+resid (final)
//      5 = fused QKV: Q/K bf16 slabs, V transposed to OutV
//      7 = bf16 acc * (1/lsum[row])  (PV)
template <int EPI>
__global__ __launch_bounds__(256)
void gemm_bt(const bf16* __restrict__ A, size_t strideA,
             const bf16* __restrict__ B, size_t strideB,
             const float* __restrict__ bias, size_t strideBias,
             void* __restrict__ Out, size_t strideOut,
             bf16* __restrict__ OutV, float* __restrict__ lsum,
             int K, int outPitch, int colBound, float scale,
             const float* __restrict__ resid, int gx, int gy)
{
    __shared__ __attribute__((aligned(16))) bf16 tA[128 * 64];
    __shared__ __attribute__((aligned(16))) bf16 tB[128 * 64];

    // XCD-contiguous remap: blocks b with b&7==c form XCD c's contiguous
    // logical range [c*T/8, (c+1)*T/8), decoded x-fastest.
    {
    }
    const int T    = gridDim.x;
    const int b    = blockIdx.x;
    const int Lidx = (b & 7) * (T >> 3) + (b >> 3);
    const int bx   = Lidx % gx;
    const int t2   = Lidx / gx;
    const int by   = t2 % gy;
    const int bz   = t2 / gy;

    A += (size_t)bz * strideA;
    B += (size_t)bz * strideB;
    if (bias) bias += (size_t)bz * strideBias;

    const int tid  = threadIdx.x;
    const int lane = tid & 63;
    const int wv   = tid >> 6;
    const int wm   = wv >> 1;
    const int wn   = wv & 1;

    f32x4 acc[4][4] = {};

    // staging: wave wv covers rows [wv*32, wv*32+32); lane L -> row L>>3,
    // LDS slot L&7 sources global chunk (L&7)^(row&7).
    const int sRow = lane >> 3;
    const int sCh  = (lane & 7) ^ sRow;
    const bf16* gA = A + (size_t)(by * 128 + wv * 32 + sRow) * K + sCh * 8;
    const bf16* gB = B + (size_t)(bx * 128 + wv * 32 + sRow) * K + sCh * 8;
    bf16* lA = &tA[(wv * 32) * 64];
    bf16* lB = &tB[(wv * 32) * 64];

    const int lr  = lane & 15;
    const int lq  = lane >> 4;
    const int rsw = lr & 7;

    for (int k0 = 0; k0 < K; k0 += 64) {
        async16(gA,                  lA);
        async16(gA + (size_t) 8 * K, lA +  8 * 64);
        async16(gA + (size_t)16 * K, lA + 16 * 64);
        async16(gA + (size_t)24 * K, lA + 24 * 64);
        async16(gB,                  lB);
        async16(gB + (size_t) 8 * K, lB +  8 * 64);
        async16(gB + (size_t)16 * K, lB + 16 * 64);
        async16(gB + (size_t)24 * K, lB + 24 * 64);
        gA += 64; gB += 64;
        __syncthreads();

        #pragma unroll
        for (int kk = 0; kk < 2; ++kk) {
            const int sl = ((kk * 4 + lq) ^ rsw) << 3;
            bf16x8 af[4], bfr[4];
            #pragma unroll
            for (int i = 0; i < 4; ++i) {
                af[i]  = *(const bf16x8*)&tA[(wm * 64 + i * 16 + lr) * 64 + sl];
                bfr[i] = *(const bf16x8*)&tB[(wn * 64 + i * 16 + lr) * 64 + sl];
            }
            #pragma unroll
            for (int i = 0; i < 4; ++i)
                #pragma unroll
                for (int j = 0; j < 4; ++j)
                    acc[i][j] = __builtin_amdgcn_mfma_f32_16x16x32_bf16(
                        af[i], bfr[j], acc[i][j], 0, 0, 0);
        }
        __syncthreads();
    }

    // C/D layout: col = lane&15, row = (lane>>4)*4 + reg  [m89/m91]
    if (EPI == 2) {
        // p = exp(s*scale) -> bf16; per-row sums -> atomicAdd lsum
        float rs[4][4] = {};    // [i][r]
        #pragma unroll
        for (int i = 0; i < 4; ++i) {
            const int rowBase = by * 128 + wm * 64 + i * 16 + lq * 4;
            #pragma unroll
            for (int j = 0; j < 4; ++j) {
                const int cg = bx * 128 + wn * 64 + j * 16 + lr;
                #pragma unroll
                for (int r = 0; r < 4; ++r) {
                    const float p = __expf(acc[i][j][r] * scale);
                    ((bf16*)Out + (size_t)bz * strideOut)
                        [(size_t)(rowBase + r) * outPitch + cg] = (bf16)p;
                    rs[i][r] += p;
                }
            }
        }
        #pragma unroll
        for (int i = 0; i < 4; ++i)
            #pragma unroll
            for (int r = 0; r < 4; ++r) {
                float v = rs[i][r];
                v += __shfl_xor(v, 1, 64);
                v += __shfl_xor(v, 2, 64);
                v += __shfl_xor(v, 4, 64);
                v += __shfl_xor(v, 8, 64);
                if (lr == 0)
                    atomicAdd(&lsum[(size_t)bz * NTOK +
                                    by * 128 + wm * 64 + i * 16 + lq * 4 + r], v);
            }
        return;
    }

    #pragma unroll
    for (int i = 0; i < 4; ++i) {
        const int rowBase = by * 128 + wm * 64 + i * 16 + lq * 4;
        float invl[4];
        if (EPI == 7) {
            #pragma unroll
            for (int r = 0; r < 4; ++r)
                invl[r] = 1.0f / lsum[(size_t)bz * NTOK + rowBase + r];
        }
        #pragma unroll
        for (int j = 0; j < 4; ++j) {
            f32x4 v = acc[i][j];
            const int cg = bx * 128 + wn * 64 + j * 16 + lr;
            if (cg >= colBound) continue;
            const float bs = bias ? bias[cg] : 0.0f;
            #pragma unroll
            for (int r = 0; r < 4; ++r) {
                const int mg = rowBase + r;
                const float val = v[r];
                if (EPI == 3) {
                    const float u = val + bs;
                    const float g = 0.5f * u * (1.0f + erff(u * 0.70710678118654752f));
                    ((bf16*)Out)[(size_t)mg * outPitch + cg] = (bf16)g;
                } else if (EPI == 4) {
                    ((float*)Out)[(size_t)mg * outPitch + cg] =
                        val + bs + resid[(size_t)mg * outPitch + cg];
                } else if (EPI == 5) {
                    const int grp = cg / D_PADN;          // 0=Q,1=K,2=V
                    const int c   = cg - grp * D_PADN;
                    const float u = val + bs;
                    if (grp < 2) {
                        if (c < D_PADK)
                            ((bf16*)Out)[(size_t)bz * 2 * SLAB_X + (size_t)grp * SLAB_X +
                                         (size_t)mg * D_PADK + c] = (bf16)u;
                    } else {
                        OutV[(size_t)bz * VSLAB + (size_t)c * NTOK + mg] = (bf16)u;
                    }
                } else { // EPI == 7
                    ((bf16*)Out + (size_t)bz * strideOut)[(size_t)mg * outPitch + cg] =
                        (bf16)(val * invl[r]);
                }
            }
        }
    }
}

// fp32 [R,C] -> zero-padded bf16 [gridDim.y, CP]
__global__ __launch_bounds__(256)
void cvt_pad(const float* __restrict__ src, int R, int C,
             bf16* __restrict__ dst, int CP)
{
    const int c = blockIdx.x * 256 + threadIdx.x;
    const int r = blockIdx.y;
    if (c >= CP) return;
    const float v = (r < R && c < C) ? src[(size_t)r * C + c] : 0.0f;
    dst[(size_t)r * CP + c] = (bf16)v;
}

__global__ __launch_bounds__(256)
void pad_bias(const float* __restrict__ src, int n, float* __restrict__ dst, int np)
{
    const int i = blockIdx.x * 256 + threadIdx.x;
    if (i < np) dst[i] = (i < n) ? src[i] : 0.0f;
}

__global__ __launch_bounds__(256)
void zero_f32(float* __restrict__ p, int n)
{
    const int i = blockIdx.x * 256 + threadIdx.x;
    if (i < n) p[i] = 0.0f;
}

// ---------------------------------------------------------------------------
// fixed workspace (bytes):
//   WQKV(3*1152x1088) 0..7,520,256  WE ..16,711,680  WO ..26,443,776
//   BQKV ..26,457,600  BE ..26,474,496  L(16384 f32) ..26,540,032
//   XBF(16384x1088; attn overwrites in place) ..62,191,616
//   VT(8x1152x2048) ..99,940,352 = OFF_SCR.  Scratch adaptive.
// ---------------------------------------------------------------------------
#define OFF_WQKV   0u
#define OFF_WE     7520256u
#define OFF_WO     16711680u
#define OFF_BQKV   26443776u
#define OFF_BE     26457600u
#define OFF_L      26474496u
#define OFF_XBF    26540032u
#define OFF_VT     62191616u
#define OFF_SCR    99940352u
#define QS_BYTES   8912896u     // per-batch Q+K slabs
#define SS_BYTES   8388608u     // per-batch bf16 exp-score slab

extern "C" void kernel_launch(void* const* d_in, const int* in_sizes, int n_in,
                              void* d_out, int out_size, void* d_ws, size_t ws_size,
                              hipStream_t stream)
{
    const float* x  = (const float*)d_in[0];
    const float* Wq = (const float*)d_in[1];
    const float* bq = (const float*)d_in[2];
    const float* Wk = (const float*)d_in[3];
    const float* bk = (const float*)d_in[4];
    const float* Wv = (const float*)d_in[5];
    const float* bv = (const float*)d_in[6];
    const float* We = (const float*)d_in[7];
    const float* be = (const float*)d_in[8];
    const float* Wo = (const float*)d_in[9];
    const float* bo = (const float*)d_in[10];

    char* ws = (char*)d_ws;
    bf16*  Wqkv = (bf16*)(ws + OFF_WQKV);
    bf16*  WeP  = (bf16*)(ws + OFF_WE);
    bf16*  WoP  = (bf16*)(ws + OFF_WO);
    float* Bqkv = (float*)(ws + OFF_BQKV);
    float* BeP  = (float*)(ws + OFF_BE);
    float* Lb   = (float*)(ws + OFF_L);
    bf16*  Xbf  = (bf16*)(ws + OFF_XBF);
    bf16*  Vt   = (bf16*)(ws + OFF_VT);
    char*  scr  = ws + OFF_SCR;

    const size_t avail = ws_size > OFF_SCR ? ws_size - OFF_SCR : 0;
    const size_t perG  = (size_t)QS_BYTES + SS_BYTES;
    int G = (avail >= 8 * perG) ? 8 : (avail >= 4 * perG) ? 4
          : (avail >= 2 * perG) ? 2 : 1;
    int R = (avail >= 69206016u) ? 8192 : (avail >= 34603008u) ? 4096 : 2048;

    bf16* Qs = (bf16*)scr;                                // [G][2] Q,K slabs
    bf16* Ss = (bf16*)(scr + (size_t)G * QS_BYTES);       // [G] exp-score slabs
    bf16* Hb = (bf16*)scr;                                // FFN phase alias

    const dim3 blk(256);
    const float inv_sqrt_d = (float)(1.0 / sqrt((double)D_REAL));

    // ---- convert + pad to bf16; zero row-sum accumulator ----
    cvt_pad<<<dim3(5, MTOT), blk, 0, stream>>>(x, MTOT, D_REAL, Xbf, D_PADK);
    cvt_pad<<<dim3(5, D_PADN), blk, 0, stream>>>(Wq, D_REAL, D_REAL, Wqkv, D_PADK);
    cvt_pad<<<dim3(5, D_PADN), blk, 0, stream>>>(Wk, D_REAL, D_REAL, Wqkv + WSLAB, D_PADK);
    cvt_pad<<<dim3(5, D_PADN), blk, 0, stream>>>(Wv, D_REAL, D_REAL, Wqkv + 2 * WSLAB, D_PADK);
    cvt_pad<<<dim3(5, H_PAD), blk, 0, stream>>>(We, H_REAL, D_REAL, WeP, D_PADK);
    cvt_pad<<<dim3(17, D_PADN), blk, 0, stream>>>(Wo, D_REAL, H_REAL, WoP, H_PAD);
    pad_bias<<<dim3(5), blk, 0, stream>>>(bq, D_REAL, Bqkv, D_PADN);
    pad_bias<<<dim3(5), blk, 0, stream>>>(bk, D_REAL, Bqkv + D_PADN, D_PADN);
    pad_bias<<<dim3(5), blk, 0, stream>>>(bv, D_REAL, Bqkv + 2 * D_PADN, D_PADN);
    pad_bias<<<dim3(17), blk, 0, stream>>>(be, H_REAL, BeP, H_PAD);
    zero_f32<<<dim3(64), blk, 0, stream>>>(Lb, MTOT);

    // ---- attention, G batches per iteration ----
    for (int g0 = 0; g0 < NB; g0 += G) {
        // fused QKV projection: cols [0,1152)=Q, [1152,2304)=K, [2304,3456)=V^T
        gemm_bt<5><<<dim3(27 * 16 * G), blk, 0, stream>>>(
            Xbf + (size_t)g0 * SLAB_X, SLAB_X, Wqkv, 0, Bqkv, 0,
            Qs, 0, Vt + (size_t)g0 * VSLAB, nullptr,
            D_PADK, 0, 3456, 1.0f, nullptr, 27, 16);
        // P = exp(QK^T * inv_sqrt_d) bf16 + row sums
        gemm_bt<2><<<dim3(16 * 16 * G), blk, 0, stream>>>(
            Qs, 2 * SLAB_X, Qs + SLAB_X, 2 * SLAB_X, nullptr, 0,
            Ss, SLAB_S, nullptr, Lb + (size_t)g0 * NTOK,
            D_PADK, NTOK, NTOK, inv_sqrt_d, nullptr, 16, 16);
        // attn = (P @ Vt^T) / l -> overwrite Xbf slab
        gemm_bt<7><<<dim3(9 * 16 * G), blk, 0, stream>>>(
            Ss, SLAB_S, Vt + (size_t)g0 * VSLAB, VSLAB, nullptr, 0,
            Xbf + (size_t)g0 * SLAB_X, SLAB_X, nullptr, Lb + (size_t)g0 * NTOK,
            NTOK, D_PADK, D_PADK, 1.0f, nullptr, 9, 16);
    }

    // ---- FFN in R-row chunks (Hb stays L3-resident) ----
    for (int r0 = 0; r0 < MTOT; r0 += R) {
        gemm_bt<3><<<dim3(33 * (R / 128)), blk, 0, stream>>>(
            Xbf + (size_t)r0 * D_PADK, 0, WeP, 0, BeP, 0,
            Hb, 0, nullptr, nullptr,
            D_PADK, H_PAD, H_PAD, 1.0f, nullptr, 33, R / 128);
        gemm_bt<4><<<dim3(9 * (R / 128)), blk, 0, stream>>>(
            Hb, 0, WoP, 0, bo, 0,
            (float*)d_out + (size_t)r0 * D_REAL, 0, nullptr, nullptr,
            H_PAD, D_REAL, D_REAL, 1.0f, x + (size_t)r0 * D_REAL, 9, R / 128);
    }
}